// Round 6
// baseline (121.598 us; speedup 1.0000x reference)
//
#include <hip/hip_runtime.h>
#include <stdint.h>

#define NLOC 469
#define NCLS 80
#define NFLAT 37520
#define TOPK 1000
#define NWORD 16         // 1000 bits -> 16 uint64 words
#define NBIN 32768       // 15-bit histogram over key top bits
#define CAP 2048         // candidate capacity (LDS)

typedef unsigned long long u64;

__device__ __forceinline__ float sigm(float x) { return 1.0f / (1.0f + expf(-x)); }

// order-preserving float -> uint32 (greater float => greater uint)
__device__ __forceinline__ uint32_t f2o(float f) {
    uint32_t u = __float_as_uint(f);
    return (u & 0x80000000u) ? ~u : (u | 0x80000000u);
}

// ---------------------------------------------------------------- decode
__global__ void decode_kernel(
    const float* __restrict__ s0, const float* __restrict__ l0, const float* __restrict__ c0,
    const float* __restrict__ s1, const float* __restrict__ l1, const float* __restrict__ c1,
    const float* __restrict__ s2, const float* __restrict__ l2, const float* __restrict__ c2,
    u64* __restrict__ keys, float4* __restrict__ bbox)
{
    int t = blockIdx.x * blockDim.x + threadIdx.x;
    if (t < NFLAT) {
        int p = t / NCLS;
        int k = t - p * NCLS;
        int c = k + 1;                       // class channel (0 = background, dropped)
        const float* sr; const float* cr; int local, hw;
        if (p < 350)      { sr = s0; cr = c0; local = p;       hw = 350; }
        else if (p < 441) { sr = s1; cr = c1; local = p - 350; hw = 91;  }
        else              { sr = s2; cr = c2; local = p - 441; hw = 28;  }
        float val = sqrtf(sigm(sr[c * hw + local]) * sigm(cr[local]));
        float masked = (val >= 0.05f) ? val : -1.0f;
        // key: value-major, tie -> lower index wins (larger low word)
        keys[t] = ((u64)f2o(masked) << 32) | (u64)(0xFFFFFFFFu - (uint32_t)t);
    }
    if (t < NLOC) {
        int p = t;
        const float* lr; int local, hw, w; float is;
        if (p < 350)      { lr = l0; local = p;       hw = 350; w = 25; is = 16.0f; }
        else if (p < 441) { lr = l1; local = p - 350; hw = 91;  w = 13; is = 32.0f; }
        else              { lr = l2; local = p - 441; hw = 28;  w = 7;  is = 64.0f; }
        int y = local / w, x = local - y * w;
        float px = ((float)x + 0.5f) * is;
        float py = ((float)y + 0.5f) * is;
        float L = lr[local] * is;
        float T = lr[hw + local] * is;
        float R = lr[2 * hw + local] * is;
        float B = lr[3 * hw + local] * is;
        bbox[p] = make_float4(px - L, py - T, px + R, py + B);
    }
}

// ----------------------------------------- fused all-LDS top-k (1 block)
__global__ void __launch_bounds__(1024) topk_kernel(
    const u64* __restrict__ keys,
    float* __restrict__ top_val, int* __restrict__ top_idx)
{
    __shared__ int histL[NBIN];      // 128 KB: counts -> bin-start -> bin-end
    __shared__ int scanbuf[1024];    // 4 KB
    __shared__ u64 candL[CAP];       // 16 KB, bin-segmented after scatter
    __shared__ int bstar_s;
    int tid = threadIdx.x;
    for (int z = tid; z < NBIN; z += 1024) histL[z] = 0;
    __syncthreads();
    for (int t = tid; t < NFLAT; t += 1024)
        atomicAdd(&histL[(int)(keys[t] >> 49)], 1);
    __syncthreads();
    // thread tid owns bins [base, base+32); tid=0 owns the HIGHEST bins
    int base = NBIN - 32 * (tid + 1);
    int r[32];
    int gsum = 0;
    #pragma unroll
    for (int k = 0; k < 32; ++k) { r[k] = histL[base + k]; gsum += r[k]; }
    scanbuf[tid] = gsum;
    __syncthreads();
    for (int off = 1; off < 1024; off <<= 1) {   // Hillis-Steele inclusive scan
        int v = (tid >= off) ? scanbuf[tid - off] : 0;
        __syncthreads();
        scanbuf[tid] += v;
        __syncthreads();
    }
    int incl = scanbuf[tid];
    int cumAbove = incl - gsum;   // keys in bins above my range
    if (cumAbove < TOPK && incl >= TOPK) {       // exactly one thread crosses
        int running = cumAbove;
        #pragma unroll
        for (int k = 31; k >= 0; --k) {          // walk own bins descending (regs)
            if (running + r[k] >= TOPK) { bstar_s = base + k; break; }
            running += r[k];
        }
    }
    // in-place convert own bins to start offsets (descending bin-major layout)
    {
        int run = cumAbove;
        #pragma unroll
        for (int k = 31; k >= 0; --k) { histL[base + k] = run; run += r[k]; }
    }
    __syncthreads();
    int Bstar = bstar_s;
    // counting-sort scatter of candidates: cursors turn start(b) into end(b)
    for (int t = tid; t < NFLAT; t += 1024) {
        u64 k = keys[t];
        int b = (int)(k >> 49);
        if (b >= Bstar) {
            int pos = atomicAdd(&histL[b], 1);
            if (pos < CAP) candL[pos] = k;
        }
    }
    __syncthreads();
    int C = min(histL[Bstar], CAP);   // end(Bstar) == total candidate count
    // exact rank = segL (#cands in higher bins) + within-segment count
    for (int p = tid; p < C; p += 1024) {
        u64 k = candL[p];
        int b = (int)(k >> 49);
        int segL = (b == NBIN - 1) ? 0 : min(histL[b + 1], CAP);
        int segR = min(histL[b], CAP);
        int cnt = segL;
        for (int q = segL; q < segR; ++q)
            cnt += (candL[q] > k) ? 1 : 0;
        if (cnt < TOPK) {
            uint32_t o = (uint32_t)(k >> 32);
            uint32_t u = (o & 0x80000000u) ? (o ^ 0x80000000u) : ~o;  // inverse f2o
            top_val[cnt] = __uint_as_float(u);
            top_idx[cnt] = (int)(0xFFFFFFFFu - (uint32_t)(k & 0xFFFFFFFFu));
        }
    }
}

// --------------------------- per-block redundant prep + suppression matrix
__global__ void maskprep_kernel(const int* __restrict__ top_idx,
                                const float4* __restrict__ bbox,
                                u64* __restrict__ mask)
{
    __shared__ float4 sboxL[TOPK];   // 16000 B
    __shared__ float sareaL[TOPK];
    __shared__ int   labL[TOPK];
    __shared__ float redL[4];
    int tid = threadIdx.x;
    float m = -3.0e38f;
    for (int j = tid; j < TOPK; j += 256) {
        int idx = top_idx[j];
        int p = idx / NCLS;
        int lab = idx - p * NCLS;
        float4 b = bbox[p];
        sboxL[j] = b; labL[j] = lab;
        m = fmaxf(m, fmaxf(fmaxf(b.x, b.y), fmaxf(b.z, b.w)));
    }
    for (int o = 32; o > 0; o >>= 1) m = fmaxf(m, __shfl_down(m, o, 64));
    if ((tid & 63) == 0) redL[tid >> 6] = m;
    __syncthreads();
    float Mp1 = fmaxf(fmaxf(redL[0], redL[1]), fmaxf(redL[2], redL[3])) + 1.0f;
    for (int j = tid; j < TOPK; j += 256) {
        float off = (float)labL[j] * Mp1;
        float4 b = sboxL[j];
        float4 s = make_float4(b.x + off, b.y + off, b.z + off, b.w + off);
        sboxL[j] = s;
        sareaL[j] = fmaxf(s.z - s.x, 0.f) * fmaxf(s.w - s.y, 0.f);
    }
    __syncthreads();
    int g = blockIdx.x * 256 + tid;
    if (g < TOPK * NWORD) {
        int i = g >> 4, w = g & 15;
        float4 si = sboxL[i]; float ai = sareaL[i];
        int j0 = w * 64, j1 = min(j0 + 64, TOPK);
        u64 bits = 0;
        for (int j = max(j0, i + 1); j < j1; ++j) {
            float4 sj = sboxL[j];
            float ltx = fmaxf(si.x, sj.x), lty = fmaxf(si.y, sj.y);
            float rbx = fminf(si.z, sj.z), rby = fminf(si.w, sj.w);
            float iw = fmaxf(rbx - ltx, 0.f), ih = fmaxf(rby - lty, 0.f);
            float inter = iw * ih;
            float iou = inter / fmaxf(ai + sareaL[j] - inter, 1e-9f);
            if (iou > 0.6f) bits |= 1ull << (j - j0);
        }
        mask[g] = bits;
    }
}

// ---- greedy scan: 8-row double-buffered register pipeline + output write
__global__ void __launch_bounds__(1024) scan_out_kernel(
    const u64* __restrict__ mask,
    const float* __restrict__ top_val, const int* __restrict__ top_idx,
    const float4* __restrict__ bbox, float* __restrict__ out)
{
    __shared__ u64 smask[TOPK * NWORD];  // 128000 B
    __shared__ u64 skeep[NWORD];
    __shared__ u64 validwL[NWORD];
    int tid = threadIdx.x;
    float tv = (tid < TOPK) ? top_val[tid] : -1.0f;
    u64 bal = __ballot(tid < TOPK && tv >= 0.05f);
    if ((tid & 63) == 0) validwL[tid >> 6] = bal;
    for (int g = tid; g < TOPK * NWORD; g += 1024) smask[g] = mask[g];
    __syncthreads();
    if (tid < 64) {
        int lw = tid & 15;
        u64 sup = 0;                 // lanes 0-15: suppressed word lw
        u64 rA[8], rcA[8], rB[8], rcB[8];

#define LOADG(buf, rcbuf, i0)                                   \
        _Pragma("unroll")                                       \
        for (int g = 0; g < 8; ++g) {                           \
            buf[g]   = smask[((i0) + g) * NWORD + lw];          \
            rcbuf[g] = smask[((i0) + g) * NWORD + c];           \
        }
#define PROCG(buf, rcbuf, b0)                                   \
        _Pragma("unroll")                                       \
        for (int g = 0; g < 8; ++g) {                           \
            u64 bit = 1ull << ((b0) + g);                       \
            u64 m = ((vw & bit) && !(cur & bit)) ? ~0ull : 0ull;\
            cur |= rcbuf[g] & m;                                \
            sup |= buf[g] & m;                                  \
            kw  |= bit & m;                                     \
        }

        for (int c = 0; c < NWORD; ++c) {
            u64 cur = __shfl(sup, c, 64);    // suppressed bits of chunk c
            u64 vw = validwL[c];
            u64 kw = 0;
            int i0 = c * 64;
            int nb = min(64, TOPK - i0);     // 64, or 40 for c=15 (both %8==0)
            LOADG(rA, rcA, i0);
            for (int b0 = 0; b0 < nb; b0 += 16) {
                if (b0 + 8 < nb)  LOADG(rB, rcB, i0 + b0 + 8);
                PROCG(rA, rcA, b0);
                if (b0 + 16 < nb) LOADG(rA, rcA, i0 + b0 + 16);
                if (b0 + 8 < nb)  PROCG(rB, rcB, b0 + 8);
            }
            if (tid == 0) skeep[c] = kw;
        }
#undef LOADG
#undef PROCG
    }
    __syncthreads();
    int j = tid;
    if (j < TOPK) {
        int idx = top_idx[j];
        int p = idx / NCLS;
        int lab = idx - p * NCLS;
        float4 b = bbox[p];
        bool kp = (skeep[j >> 6] >> (j & 63)) & 1ull;
        float x1 = fminf(fmaxf(b.x, 0.f), 224.f);
        float y1 = fminf(fmaxf(b.y, 0.f), 398.f);
        float x2 = fminf(fmaxf(b.z, 0.f), 224.f);
        float y2 = fminf(fmaxf(b.w, 0.f), 398.f);
        kp = kp && ((x2 - x1) >= 1e-5f) && ((y2 - y1) >= 1e-5f);
        out[j * 4 + 0] = kp ? x1 : 0.f;
        out[j * 4 + 1] = kp ? y1 : 0.f;
        out[j * 4 + 2] = kp ? x2 : 0.f;
        out[j * 4 + 3] = kp ? y2 : 0.f;
        out[4 * TOPK + j] = kp ? tv : -1.0f;
        out[5 * TOPK + j] = (float)lab;
        out[6 * TOPK + j] = kp ? 1.0f : 0.0f;
    }
}

extern "C" void kernel_launch(void* const* d_in, const int* in_sizes, int n_in,
                              void* d_out, int out_size, void* d_ws, size_t ws_size,
                              hipStream_t stream)
{
    const float* s0 = (const float*)d_in[0];
    const float* l0 = (const float*)d_in[1];
    const float* c0 = (const float*)d_in[2];
    const float* s1 = (const float*)d_in[3];
    const float* l1 = (const float*)d_in[4];
    const float* c1 = (const float*)d_in[5];
    const float* s2 = (const float*)d_in[6];
    const float* l2 = (const float*)d_in[7];
    const float* c2 = (const float*)d_in[8];

    uint8_t* ws = (uint8_t*)d_ws;
    u64*    keys = (u64*)   (ws);              // 37520*8  = 300160 B
    float4* bbox = (float4*)(ws + 300160);     // 469*16   =   7504 B
    u64*    mask = (u64*)   (ws + 307664);     // 16000*8  = 128000 B
    float*  tval = (float*) (ws + 435664);     // 1000*4
    int*    tidx = (int*)   (ws + 439664);     // 1000*4  -> 443664 B total

    decode_kernel<<<dim3((NFLAT + 255) / 256), 256, 0, stream>>>(
        s0, l0, c0, s1, l1, c1, s2, l2, c2, keys, bbox);
    topk_kernel<<<1, 1024, 0, stream>>>(keys, tval, tidx);
    maskprep_kernel<<<dim3((TOPK * NWORD + 255) / 256), 256, 0, stream>>>(tidx, bbox, mask);
    scan_out_kernel<<<1, 1024, 0, stream>>>(mask, tval, tidx, bbox, (float*)d_out);
}

// Round 7
// 90.423 us; speedup vs baseline: 1.3448x; 1.3448x over previous
//
#include <hip/hip_runtime.h>
#include <stdint.h>

#define NLOC 469
#define NCLS 80
#define NFLAT 37520
#define TOPK 1000
#define NWORD 16         // 1000 bits -> 16 uint64 words
#define NBIN 32768       // 15-bit histogram over key top bits
#define CAP 2048         // candidate capacity (LDS)

typedef unsigned long long u64;

__device__ __forceinline__ float sigm(float x) { return 1.0f / (1.0f + expf(-x)); }

// order-preserving float -> uint32 (greater float => greater uint)
__device__ __forceinline__ uint32_t f2o(float f) {
    uint32_t u = __float_as_uint(f);
    return (u & 0x80000000u) ? ~u : (u | 0x80000000u);
}

// ---------------------------------------------------------------- decode
__global__ void decode_kernel(
    const float* __restrict__ s0, const float* __restrict__ l0, const float* __restrict__ c0,
    const float* __restrict__ s1, const float* __restrict__ l1, const float* __restrict__ c1,
    const float* __restrict__ s2, const float* __restrict__ l2, const float* __restrict__ c2,
    u64* __restrict__ keys, float4* __restrict__ bbox)
{
    int t = blockIdx.x * blockDim.x + threadIdx.x;
    if (t < NFLAT) {
        int p = t / NCLS;
        int k = t - p * NCLS;
        int c = k + 1;                       // class channel (0 = background, dropped)
        const float* sr; const float* cr; int local, hw;
        if (p < 350)      { sr = s0; cr = c0; local = p;       hw = 350; }
        else if (p < 441) { sr = s1; cr = c1; local = p - 350; hw = 91;  }
        else              { sr = s2; cr = c2; local = p - 441; hw = 28;  }
        float val = sqrtf(sigm(sr[c * hw + local]) * sigm(cr[local]));
        float masked = (val >= 0.05f) ? val : -1.0f;
        // key: value-major, tie -> lower index wins (larger low word)
        keys[t] = ((u64)f2o(masked) << 32) | (u64)(0xFFFFFFFFu - (uint32_t)t);
    }
    if (t < NLOC) {
        int p = t;
        const float* lr; int local, hw, w; float is;
        if (p < 350)      { lr = l0; local = p;       hw = 350; w = 25; is = 16.0f; }
        else if (p < 441) { lr = l1; local = p - 350; hw = 91;  w = 13; is = 32.0f; }
        else              { lr = l2; local = p - 441; hw = 28;  w = 7;  is = 64.0f; }
        int y = local / w, x = local - y * w;
        float px = ((float)x + 0.5f) * is;
        float py = ((float)y + 0.5f) * is;
        float L = lr[local] * is;
        float T = lr[hw + local] * is;
        float R = lr[2 * hw + local] * is;
        float B = lr[3 * hw + local] * is;
        bbox[p] = make_float4(px - L, py - T, px + R, py + B);
    }
}

// ----------------------------------------- fused all-LDS top-k (1 block)
__global__ void __launch_bounds__(1024) topk_kernel(
    const u64* __restrict__ keys,
    float* __restrict__ top_val, int* __restrict__ top_idx)
{
    __shared__ int histL[NBIN];      // 128 KB: counts -> bin-start -> bin-end
    __shared__ int scanbuf[1024];    // 4 KB
    __shared__ u64 candL[CAP];       // 16 KB, bin-segmented after scatter
    __shared__ int bstar_s;
    int tid = threadIdx.x;
    for (int z = tid; z < NBIN; z += 1024) histL[z] = 0;
    __syncthreads();
    for (int t = tid; t < NFLAT; t += 1024)
        atomicAdd(&histL[(int)(keys[t] >> 49)], 1);
    __syncthreads();
    // thread tid owns bins [base, base+32); tid=0 owns the HIGHEST bins
    int base = NBIN - 32 * (tid + 1);
    int r[32];
    int gsum = 0;
    #pragma unroll
    for (int k = 0; k < 32; ++k) { r[k] = histL[base + k]; gsum += r[k]; }
    scanbuf[tid] = gsum;
    __syncthreads();
    for (int off = 1; off < 1024; off <<= 1) {   // Hillis-Steele inclusive scan
        int v = (tid >= off) ? scanbuf[tid - off] : 0;
        __syncthreads();
        scanbuf[tid] += v;
        __syncthreads();
    }
    int incl = scanbuf[tid];
    int cumAbove = incl - gsum;   // keys in bins above my range
    if (cumAbove < TOPK && incl >= TOPK) {       // exactly one thread crosses
        int running = cumAbove;
        #pragma unroll
        for (int k = 31; k >= 0; --k) {          // walk own bins descending (regs)
            if (running + r[k] >= TOPK) { bstar_s = base + k; break; }
            running += r[k];
        }
    }
    // in-place convert own bins to start offsets (descending bin-major layout)
    {
        int run = cumAbove;
        #pragma unroll
        for (int k = 31; k >= 0; --k) { histL[base + k] = run; run += r[k]; }
    }
    __syncthreads();
    int Bstar = bstar_s;
    // counting-sort scatter of candidates: cursors turn start(b) into end(b)
    for (int t = tid; t < NFLAT; t += 1024) {
        u64 k = keys[t];
        int b = (int)(k >> 49);
        if (b >= Bstar) {
            int pos = atomicAdd(&histL[b], 1);
            if (pos < CAP) candL[pos] = k;
        }
    }
    __syncthreads();
    int C = min(histL[Bstar], CAP);   // end(Bstar) == total candidate count
    // exact rank = segL (#cands in higher bins) + within-segment count
    for (int p = tid; p < C; p += 1024) {
        u64 k = candL[p];
        int b = (int)(k >> 49);
        int segL = (b == NBIN - 1) ? 0 : min(histL[b + 1], CAP);
        int segR = min(histL[b], CAP);
        int cnt = segL;
        for (int q = segL; q < segR; ++q)
            cnt += (candL[q] > k) ? 1 : 0;
        if (cnt < TOPK) {
            uint32_t o = (uint32_t)(k >> 32);
            uint32_t u = (o & 0x80000000u) ? (o ^ 0x80000000u) : ~o;  // inverse f2o
            top_val[cnt] = __uint_as_float(u);
            top_idx[cnt] = (int)(0xFFFFFFFFu - (uint32_t)(k & 0xFFFFFFFFu));
        }
    }
}

// --------------------------- per-block redundant prep + suppression matrix
__global__ void maskprep_kernel(const int* __restrict__ top_idx,
                                const float4* __restrict__ bbox,
                                u64* __restrict__ mask)
{
    __shared__ float4 sboxL[TOPK];   // 16000 B
    __shared__ float sareaL[TOPK];
    __shared__ int   labL[TOPK];
    __shared__ float redL[4];
    int tid = threadIdx.x;
    float m = -3.0e38f;
    for (int j = tid; j < TOPK; j += 256) {
        int idx = top_idx[j];
        int p = idx / NCLS;
        int lab = idx - p * NCLS;
        float4 b = bbox[p];
        sboxL[j] = b; labL[j] = lab;
        m = fmaxf(m, fmaxf(fmaxf(b.x, b.y), fmaxf(b.z, b.w)));
    }
    for (int o = 32; o > 0; o >>= 1) m = fmaxf(m, __shfl_down(m, o, 64));
    if ((tid & 63) == 0) redL[tid >> 6] = m;
    __syncthreads();
    float Mp1 = fmaxf(fmaxf(redL[0], redL[1]), fmaxf(redL[2], redL[3])) + 1.0f;
    for (int j = tid; j < TOPK; j += 256) {
        float off = (float)labL[j] * Mp1;
        float4 b = sboxL[j];
        float4 s = make_float4(b.x + off, b.y + off, b.z + off, b.w + off);
        sboxL[j] = s;
        sareaL[j] = fmaxf(s.z - s.x, 0.f) * fmaxf(s.w - s.y, 0.f);
    }
    __syncthreads();
    int g = blockIdx.x * 256 + tid;
    if (g < TOPK * NWORD) {
        int i = g >> 4, w = g & 15;
        float4 si = sboxL[i]; float ai = sareaL[i];
        int j0 = w * 64, j1 = min(j0 + 64, TOPK);
        u64 bits = 0;
        for (int j = max(j0, i + 1); j < j1; ++j) {
            float4 sj = sboxL[j];
            float ltx = fmaxf(si.x, sj.x), lty = fmaxf(si.y, sj.y);
            float rbx = fminf(si.z, sj.z), rby = fminf(si.w, sj.w);
            float iw = fmaxf(rbx - ltx, 0.f), ih = fmaxf(rby - lty, 0.f);
            float inter = iw * ih;
            float iou = inter / fmaxf(ai + sareaL[j] - inter, 1e-9f);
            if (iou > 0.6f) bits |= 1ull << (j - j0);
        }
        mask[g] = bits;
    }
}

// ---- greedy scan: u32x32-lane ownership, scalar keep-chain, 2 VALU/row
__global__ void __launch_bounds__(1024) scan_out_kernel(
    const u64* __restrict__ mask,
    const float* __restrict__ top_val, const int* __restrict__ top_idx,
    const float4* __restrict__ bbox, float* __restrict__ out)
{
    __shared__ uint32_t smask[1024 * 32];   // 131072 B; rows 1000..1023 zeroed
    __shared__ uint32_t skeep32[32];
    __shared__ uint32_t validw32[32];
    int tid = threadIdx.x;
    float tv = (tid < TOPK) ? top_val[tid] : -1.0f;
    u64 bal = __ballot(tid < TOPK && tv >= 0.05f);
    if ((tid & 63) == 0) {
        validw32[(tid >> 6) * 2]     = (uint32_t)bal;
        validw32[(tid >> 6) * 2 + 1] = (uint32_t)(bal >> 32);
    }
    u64* smask64 = (u64*)smask;
    for (int g = tid; g < 1024 * NWORD; g += 1024)
        smask64[g] = (g < TOPK * NWORD) ? mask[g] : 0ull;
    __syncthreads();
    if (tid < 32) {
        const int lane = tid;          // owns u32 word `lane` of the 1024-bit state
        uint32_t sup = 0;              // suppressed bits, word `lane`
        uint32_t rA[32], rB[32];

// process one 32-row chunk held in register array R
#define PROC(R, cc) {                                                        \
        uint32_t avail = validw32[cc] & ~(uint32_t)__builtin_amdgcn_readlane((int)sup, cc); \
        uint32_t kw = 0;                                                     \
        _Pragma("unroll")                                                    \
        for (int b = 0; b < 32; ++b) {                                       \
            uint32_t rc = (uint32_t)__builtin_amdgcn_readlane((int)R[b], cc);\
            uint32_t kp = (avail >> b) & 1u;                                 \
            uint32_t m = 0u - kp;                                            \
            sup |= R[b] & m;                                                 \
            avail &= ~(rc & m);                                              \
            kw |= kp << b;                                                   \
        }                                                                    \
        if (lane == 0) skeep32[cc] = kw;                                     \
}
#define LOADC(R, cc) {                                                       \
        _Pragma("unroll")                                                    \
        for (int b = 0; b < 32; ++b) R[b] = smask[((cc) * 32 + b) * 32 + lane]; \
}
        LOADC(rA, 0);
        for (int c = 0; c < 32; c += 2) {
            LOADC(rB, c + 1);
            PROC(rA, c);
            if (c + 2 < 32) LOADC(rA, c + 2);
            PROC(rB, c + 1);
        }
#undef PROC
#undef LOADC
    }
    __syncthreads();
    int j = tid;
    if (j < TOPK) {
        int idx = top_idx[j];
        int p = idx / NCLS;
        int lab = idx - p * NCLS;
        float4 b = bbox[p];
        bool kp = (skeep32[j >> 5] >> (j & 31)) & 1u;
        float x1 = fminf(fmaxf(b.x, 0.f), 224.f);
        float y1 = fminf(fmaxf(b.y, 0.f), 398.f);
        float x2 = fminf(fmaxf(b.z, 0.f), 224.f);
        float y2 = fminf(fmaxf(b.w, 0.f), 398.f);
        kp = kp && ((x2 - x1) >= 1e-5f) && ((y2 - y1) >= 1e-5f);
        out[j * 4 + 0] = kp ? x1 : 0.f;
        out[j * 4 + 1] = kp ? y1 : 0.f;
        out[j * 4 + 2] = kp ? x2 : 0.f;
        out[j * 4 + 3] = kp ? y2 : 0.f;
        out[4 * TOPK + j] = kp ? tv : -1.0f;
        out[5 * TOPK + j] = (float)lab;
        out[6 * TOPK + j] = kp ? 1.0f : 0.0f;
    }
}

extern "C" void kernel_launch(void* const* d_in, const int* in_sizes, int n_in,
                              void* d_out, int out_size, void* d_ws, size_t ws_size,
                              hipStream_t stream)
{
    const float* s0 = (const float*)d_in[0];
    const float* l0 = (const float*)d_in[1];
    const float* c0 = (const float*)d_in[2];
    const float* s1 = (const float*)d_in[3];
    const float* l1 = (const float*)d_in[4];
    const float* c1 = (const float*)d_in[5];
    const float* s2 = (const float*)d_in[6];
    const float* l2 = (const float*)d_in[7];
    const float* c2 = (const float*)d_in[8];

    uint8_t* ws = (uint8_t*)d_ws;
    u64*    keys = (u64*)   (ws);              // 37520*8  = 300160 B
    float4* bbox = (float4*)(ws + 300160);     // 469*16   =   7504 B
    u64*    mask = (u64*)   (ws + 307664);     // 16000*8  = 128000 B
    float*  tval = (float*) (ws + 435664);     // 1000*4
    int*    tidx = (int*)   (ws + 439664);     // 1000*4  -> 443664 B total

    decode_kernel<<<dim3((NFLAT + 255) / 256), 256, 0, stream>>>(
        s0, l0, c0, s1, l1, c1, s2, l2, c2, keys, bbox);
    topk_kernel<<<1, 1024, 0, stream>>>(keys, tval, tidx);
    maskprep_kernel<<<dim3((TOPK * NWORD + 255) / 256), 256, 0, stream>>>(tidx, bbox, mask);
    scan_out_kernel<<<1, 1024, 0, stream>>>(mask, tval, tidx, bbox, (float*)d_out);
}

// Round 8
// 89.340 us; speedup vs baseline: 1.3611x; 1.0121x over previous
//
#include <hip/hip_runtime.h>
#include <stdint.h>

#define NLOC 469
#define NCLS 80
#define NFLAT 37520
#define TOPK 1000
#define NWORD 16         // 1000 bits -> 16 uint64 words
#define NBIN 32768       // 15-bit histogram over key top bits
#define CAP 2048         // candidate capacity (LDS)

typedef unsigned long long u64;

__device__ __forceinline__ float sigm(float x) { return 1.0f / (1.0f + expf(-x)); }

// order-preserving float -> uint32 (greater float => greater uint)
__device__ __forceinline__ uint32_t f2o(float f) {
    uint32_t u = __float_as_uint(f);
    return (u & 0x80000000u) ? ~u : (u | 0x80000000u);
}

// ---------------------------------------------------------------- decode
__global__ void decode_kernel(
    const float* __restrict__ s0, const float* __restrict__ l0, const float* __restrict__ c0,
    const float* __restrict__ s1, const float* __restrict__ l1, const float* __restrict__ c1,
    const float* __restrict__ s2, const float* __restrict__ l2, const float* __restrict__ c2,
    u64* __restrict__ keys, float4* __restrict__ bbox, unsigned short* __restrict__ bin16)
{
    int t = blockIdx.x * blockDim.x + threadIdx.x;
    if (t < NFLAT) {
        int p = t / NCLS;
        int k = t - p * NCLS;
        int c = k + 1;                       // class channel (0 = background, dropped)
        const float* sr; const float* cr; int local, hw;
        if (p < 350)      { sr = s0; cr = c0; local = p;       hw = 350; }
        else if (p < 441) { sr = s1; cr = c1; local = p - 350; hw = 91;  }
        else              { sr = s2; cr = c2; local = p - 441; hw = 28;  }
        float val = sqrtf(sigm(sr[c * hw + local]) * sigm(cr[local]));
        float masked = (val >= 0.05f) ? val : -1.0f;
        // key: value-major, tie -> lower index wins (larger low word)
        u64 key = ((u64)f2o(masked) << 32) | (u64)(0xFFFFFFFFu - (uint32_t)t);
        keys[t] = key;
        bin16[t] = (unsigned short)(key >> 49);
    }
    if (t < NLOC) {
        int p = t;
        const float* lr; int local, hw, w; float is;
        if (p < 350)      { lr = l0; local = p;       hw = 350; w = 25; is = 16.0f; }
        else if (p < 441) { lr = l1; local = p - 350; hw = 91;  w = 13; is = 32.0f; }
        else              { lr = l2; local = p - 441; hw = 28;  w = 7;  is = 64.0f; }
        int y = local / w, x = local - y * w;
        float px = ((float)x + 0.5f) * is;
        float py = ((float)y + 0.5f) * is;
        float L = lr[local] * is;
        float T = lr[hw + local] * is;
        float R = lr[2 * hw + local] * is;
        float B = lr[3 * hw + local] * is;
        bbox[p] = make_float4(px - L, py - T, px + R, py + B);
    }
}

// ----------------------------------------- fused all-LDS top-k (1 block)
__global__ void __launch_bounds__(1024) topk_kernel(
    const u64* __restrict__ keys, const unsigned short* __restrict__ bin16,
    float* __restrict__ top_val, int* __restrict__ top_idx)
{
    __shared__ int histL[NBIN];      // 128 KB: counts -> bin-start -> bin-end
    __shared__ int scanbuf[1024];    // 4 KB
    __shared__ u64 candL[CAP];       // 16 KB, bin-segmented after scatter
    __shared__ int bstar_s;
    int tid = threadIdx.x;
    for (int z = tid; z < NBIN; z += 1024) histL[z] = 0;
    __syncthreads();
    const uint32_t* b2 = (const uint32_t*)bin16;   // 2 bins per u32
    for (int t = tid; t < NFLAT / 2; t += 1024) {
        uint32_t v = b2[t];
        atomicAdd(&histL[v & 0xffffu], 1);
        atomicAdd(&histL[v >> 16], 1);
    }
    __syncthreads();
    // thread tid owns bins [base, base+32); tid=0 owns the HIGHEST bins
    int base = NBIN - 32 * (tid + 1);
    int r[32];
    int gsum = 0;
    #pragma unroll
    for (int k = 0; k < 32; ++k) { r[k] = histL[base + k]; gsum += r[k]; }
    scanbuf[tid] = gsum;
    __syncthreads();
    for (int off = 1; off < 1024; off <<= 1) {   // Hillis-Steele inclusive scan
        int v = (tid >= off) ? scanbuf[tid - off] : 0;
        __syncthreads();
        scanbuf[tid] += v;
        __syncthreads();
    }
    int incl = scanbuf[tid];
    int cumAbove = incl - gsum;   // keys in bins above my range
    if (cumAbove < TOPK && incl >= TOPK) {       // exactly one thread crosses
        int running = cumAbove;
        #pragma unroll
        for (int k = 31; k >= 0; --k) {          // walk own bins descending (regs)
            if (running + r[k] >= TOPK) { bstar_s = base + k; break; }
            running += r[k];
        }
    }
    // in-place convert own bins to start offsets (descending bin-major layout)
    {
        int run = cumAbove;
        #pragma unroll
        for (int k = 31; k >= 0; --k) { histL[base + k] = run; run += r[k]; }
    }
    __syncthreads();
    int Bstar = bstar_s;
    // counting-sort scatter: re-read bins, gather full key only for candidates
    for (int t = tid; t < NFLAT; t += 1024) {
        int b = bin16[t];
        if (b >= Bstar) {
            int pos = atomicAdd(&histL[b], 1);
            if (pos < CAP) candL[pos] = keys[t];
        }
    }
    __syncthreads();
    int C = min(histL[Bstar], CAP);   // end(Bstar) == total candidate count
    // exact rank = segL (#cands in higher bins) + within-segment count
    for (int p = tid; p < C; p += 1024) {
        u64 k = candL[p];
        int b = (int)(k >> 49);
        int segL = (b == NBIN - 1) ? 0 : min(histL[b + 1], CAP);
        int segR = min(histL[b], CAP);
        int cnt = segL;
        for (int q = segL; q < segR; ++q)
            cnt += (candL[q] > k) ? 1 : 0;
        if (cnt < TOPK) {
            uint32_t o = (uint32_t)(k >> 32);
            uint32_t u = (o & 0x80000000u) ? (o ^ 0x80000000u) : ~o;  // inverse f2o
            top_val[cnt] = __uint_as_float(u);
            top_idx[cnt] = (int)(0xFFFFFFFFu - (uint32_t)(k & 0xFFFFFFFFu));
        }
    }
}

// --------------------------- per-block redundant prep + suppression matrix
__global__ void maskprep_kernel(const int* __restrict__ top_idx,
                                const float4* __restrict__ bbox,
                                u64* __restrict__ mask)
{
    __shared__ float4 sboxL[TOPK];   // 16000 B
    __shared__ float sareaL[TOPK];
    __shared__ int   labL[TOPK];
    __shared__ float redL[4];
    int tid = threadIdx.x;
    float m = -3.0e38f;
    for (int j = tid; j < TOPK; j += 256) {
        int idx = top_idx[j];
        int p = idx / NCLS;
        int lab = idx - p * NCLS;
        float4 b = bbox[p];
        sboxL[j] = b; labL[j] = lab;
        m = fmaxf(m, fmaxf(fmaxf(b.x, b.y), fmaxf(b.z, b.w)));
    }
    for (int o = 32; o > 0; o >>= 1) m = fmaxf(m, __shfl_down(m, o, 64));
    if ((tid & 63) == 0) redL[tid >> 6] = m;
    __syncthreads();
    float Mp1 = fmaxf(fmaxf(redL[0], redL[1]), fmaxf(redL[2], redL[3])) + 1.0f;
    for (int j = tid; j < TOPK; j += 256) {
        float off = (float)labL[j] * Mp1;
        float4 b = sboxL[j];
        float4 s = make_float4(b.x + off, b.y + off, b.z + off, b.w + off);
        sboxL[j] = s;
        sareaL[j] = fmaxf(s.z - s.x, 0.f) * fmaxf(s.w - s.y, 0.f);
    }
    __syncthreads();
    int g = blockIdx.x * 256 + tid;
    if (g < TOPK * NWORD) {
        int i = g >> 4, w = g & 15;
        float4 si = sboxL[i]; float ai = sareaL[i];
        int j0 = w * 64, j1 = min(j0 + 64, TOPK);
        u64 bits = 0;
        for (int j = max(j0, i + 1); j < j1; ++j) {
            float4 sj = sboxL[j];
            float ltx = fmaxf(si.x, sj.x), lty = fmaxf(si.y, sj.y);
            float rbx = fminf(si.z, sj.z), rby = fminf(si.w, sj.w);
            float iw = fmaxf(rbx - ltx, 0.f), ih = fmaxf(rby - lty, 0.f);
            float inter = iw * ih;
            float iou = inter / fmaxf(ai + sareaL[j] - inter, 1e-9f);
            if (iou > 0.6f) bits |= 1ull << (j - j0);
        }
        mask[g] = bits;
    }
}

// ---- greedy scan: u32x32-lane ownership, 16-row double-buffered registers
__global__ void __launch_bounds__(1024) scan_out_kernel(
    const u64* __restrict__ mask,
    const float* __restrict__ top_val, const int* __restrict__ top_idx,
    const float4* __restrict__ bbox, float* __restrict__ out)
{
    __shared__ uint32_t smask[1024 * 32];   // 131072 B; rows 1000..1023 zeroed
    __shared__ uint32_t skeep32[32];
    __shared__ uint32_t validw32[32];
    int tid = threadIdx.x;
    float tv = (tid < TOPK) ? top_val[tid] : -1.0f;
    u64 bal = __ballot(tid < TOPK && tv >= 0.05f);
    if ((tid & 63) == 0) {
        validw32[(tid >> 6) * 2]     = (uint32_t)bal;
        validw32[(tid >> 6) * 2 + 1] = (uint32_t)(bal >> 32);
    }
    u64* smask64 = (u64*)smask;
    for (int g = tid; g < 1024 * NWORD; g += 1024)
        smask64[g] = (g < TOPK * NWORD) ? mask[g] : 0ull;
    __syncthreads();
    if (tid < 32) {
        const int lane = tid;          // owns u32 word `lane` of the 1024-bit state
        uint32_t vwreg = validw32[lane];
        uint32_t sup = 0;              // suppressed bits, word `lane`
        uint32_t rA[16], rB[16];

// load 16-row half-chunk hh (rows hh*16 .. hh*16+15), word `lane` of each
#define LOADH(R, hh) {                                                        \
        _Pragma("unroll")                                                     \
        for (int b = 0; b < 16; ++b) R[b] = smask[((hh) * 16 + b) * 32 + lane]; \
}
// process 16 rows of word wc, bits [sh, sh+16)
#define PROC16(R, wc, sh) {                                                   \
        _Pragma("unroll")                                                     \
        for (int b = 0; b < 16; ++b) {                                        \
            uint32_t rc = (uint32_t)__builtin_amdgcn_readlane((int)R[b], (wc)); \
            uint32_t kp = (avail >> ((sh) + b)) & 1u;                         \
            uint32_t mm = 0u - kp;                                            \
            sup   |= R[b] & mm;                                               \
            avail &= ~(rc & mm);                                              \
            kw    |= kp << ((sh) + b);                                        \
        }                                                                     \
}
        LOADH(rA, 0);
        for (int h = 0; h < 64; h += 2) {
            const int wc = h >> 1;
            LOADH(rB, h + 1);
            uint32_t avail = (uint32_t)__builtin_amdgcn_readlane((int)vwreg, wc)
                           & ~(uint32_t)__builtin_amdgcn_readlane((int)sup, wc);
            uint32_t kw = 0;
            PROC16(rA, wc, 0);
            if (h + 2 < 64) LOADH(rA, h + 2);
            PROC16(rB, wc, 16);
            if (lane == 0) skeep32[wc] = kw;
        }
#undef PROC16
#undef LOADH
    }
    __syncthreads();
    int j = tid;
    if (j < TOPK) {
        int idx = top_idx[j];
        int p = idx / NCLS;
        int lab = idx - p * NCLS;
        float4 b = bbox[p];
        bool kp = (skeep32[j >> 5] >> (j & 31)) & 1u;
        float x1 = fminf(fmaxf(b.x, 0.f), 224.f);
        float y1 = fminf(fmaxf(b.y, 0.f), 398.f);
        float x2 = fminf(fmaxf(b.z, 0.f), 224.f);
        float y2 = fminf(fmaxf(b.w, 0.f), 398.f);
        kp = kp && ((x2 - x1) >= 1e-5f) && ((y2 - y1) >= 1e-5f);
        out[j * 4 + 0] = kp ? x1 : 0.f;
        out[j * 4 + 1] = kp ? y1 : 0.f;
        out[j * 4 + 2] = kp ? x2 : 0.f;
        out[j * 4 + 3] = kp ? y2 : 0.f;
        out[4 * TOPK + j] = kp ? tv : -1.0f;
        out[5 * TOPK + j] = (float)lab;
        out[6 * TOPK + j] = kp ? 1.0f : 0.0f;
    }
}

extern "C" void kernel_launch(void* const* d_in, const int* in_sizes, int n_in,
                              void* d_out, int out_size, void* d_ws, size_t ws_size,
                              hipStream_t stream)
{
    const float* s0 = (const float*)d_in[0];
    const float* l0 = (const float*)d_in[1];
    const float* c0 = (const float*)d_in[2];
    const float* s1 = (const float*)d_in[3];
    const float* l1 = (const float*)d_in[4];
    const float* c1 = (const float*)d_in[5];
    const float* s2 = (const float*)d_in[6];
    const float* l2 = (const float*)d_in[7];
    const float* c2 = (const float*)d_in[8];

    uint8_t* ws = (uint8_t*)d_ws;
    u64*    keys = (u64*)   (ws);              // 37520*8  = 300160 B
    float4* bbox = (float4*)(ws + 300160);     // 469*16   =   7504 B
    u64*    mask = (u64*)   (ws + 307664);     // 16000*8  = 128000 B
    float*  tval = (float*) (ws + 435664);     // 1000*4
    int*    tidx = (int*)   (ws + 439664);     // 1000*4
    unsigned short* bin16 = (unsigned short*)(ws + 443664);  // 37520*2 = 75040 -> 518704 B total

    decode_kernel<<<dim3((NFLAT + 255) / 256), 256, 0, stream>>>(
        s0, l0, c0, s1, l1, c1, s2, l2, c2, keys, bbox, bin16);
    topk_kernel<<<1, 1024, 0, stream>>>(keys, bin16, tval, tidx);
    maskprep_kernel<<<dim3((TOPK * NWORD + 255) / 256), 256, 0, stream>>>(tidx, bbox, mask);
    scan_out_kernel<<<1, 1024, 0, stream>>>(mask, tval, tidx, bbox, (float*)d_out);
}